// Round 6
// baseline (982.050 us; speedup 1.0000x reference)
//
#include <hip/hip_runtime.h>

// ---------------------------------------------------------------------------
// Round 16: duplicate-compute trans-rebalance (zero new barriers).
//   Both F and P waves compute the full gate MFMAs per phase (gates are
//   bit-identical: same operands, same FMA order). F ews rows {0,1}, P ews
//   rows {2,3} with split c-state. P additionally does the prec MFMAs and
//   ACs writes (R14 schedule); F additionally does proj + out-store.
//   Barrier structure = R14 exactly (4/step). R15's mid-barrier (+380cy each)
//   eliminated. absmax canary: 4.8828e-4. Encoder (R10) untouched.
// ---------------------------------------------------------------------------

#define S_LEN 120
#define BATCH 2048
#define NIN   6
#define H     64
#define NL    4
#define TLEN  120

#define HPAD 72            // row stride in halves (144 B)

#define FRAGS_HALF 60      // col-sliced: 12 (layer0) + 3*16
#define PACK_H8    (2 * FRAGS_HALF * 4 * 64)
#define PROJ_H8    (2 * 64)
#define NPACK      ((PACK_H8 + PROJ_H8) * 8)   // 246784 fp16 elements
#define EPACK_EL   (256 * 64 * 8)              // encoder pipeline pack
#define NTOT       (NPACK + EPACK_EL)          // 377856 (~756 KB)

// workspace byte offsets (after the weight pack)
#define WS_HOFF (768 * 1024)                   // h: 4*2048*64 fp16 = 1 MB
#define WS_COFF (WS_HOFF + 1024 * 1024)        // c: 4*2048*64 f32 = 2 MB

#define PERM(kk) ((((kk) & 3) << 4) | ((kk) >> 2))   // pi^-1
#define PI(c)    ((((c) & 15) << 2) | ((c) >> 4))    // pi

typedef _Float16 h8    __attribute__((ext_vector_type(8)));
typedef _Float16 hh2   __attribute__((ext_vector_type(2)));
typedef float    f32x4 __attribute__((ext_vector_type(4)));
typedef float    f32x2 __attribute__((ext_vector_type(2)));

__device__ __forceinline__ void bar_lgkm() {
  asm volatile("s_waitcnt lgkmcnt(0)\n\ts_barrier" ::: "memory");
}

// lane L <-> lane L^16 exchange (BitMode xor=16, and=0x1F)
__device__ __forceinline__ float swz16(float v) {
  int i = __builtin_bit_cast(int, v);
  i = __builtin_amdgcn_ds_swizzle(i, 0x401F);
  return __builtin_bit_cast(float, i);
}

// ---------------------------------------------------------------------------
// Weight pack (identical to rounds 5-15).
// ---------------------------------------------------------------------------
__global__ void prep_weights(const float* __restrict__ eWih0,
                             const float* __restrict__ eWih,
                             const float* __restrict__ eWhh,
                             const float* __restrict__ dWih0,
                             const float* __restrict__ dWih,
                             const float* __restrict__ dWhh,
                             const float* __restrict__ linW,
                             _Float16* __restrict__ wq) {
  int idx = blockIdx.x * blockDim.x + threadIdx.x;
  if (idx >= NTOT) return;

  if (idx >= NPACK) {                      // ---- encoder pipeline pack ----
    int p    = idx - NPACK;
    int j    = p & 7;
    int lane = (p >> 3) & 63;
    int fe   = p >> 9;
    int kt   = fe & 3, nt = (fe >> 2) & 15, l = fe >> 6;
    int g    = nt * 16 + (lane & 15);
    int koff = ((lane >> 4) << 3) + j;
    float v = 0.0f;
    if (l == 0) {
      if (kt == 0)      v = (koff < NIN) ? eWih0[g * NIN + koff] : 0.0f;
      else if (kt == 1) v = 0.0f;
      else { int kk = (kt - 2) * 32 + koff; v = eWhh[g * H + PERM(kk)]; }
    } else {
      if (kt < 2) { int kk = kt * 32 + koff;
                    v = eWih[((l - 1) * 256 + g) * H + PERM(kk)]; }
      else        { int kk = (kt - 2) * 32 + koff;
                    v = eWhh[(l * 256 + g) * H + PERM(kk)]; }
    }
    wq[idx] = (_Float16)v;
    return;
  }

  if (idx >= PACK_H8 * 8) {                // ---- linW A-layout frags ----
    int p    = idx - PACK_H8 * 8;
    int j    = p & 7;
    int lane = (p >> 3) & 63;
    int fr   = p >> 9;
    int m    = lane & 15;
    int k    = fr * 32 + ((lane >> 4) << 3) + j;
    wq[idx] = (_Float16)((m < NIN) ? linW[m * H + k] : 0.0f);
    return;
  }

  // ---- col-sliced pack (decoder uses dec half) ----
  const int j    = idx & 7;
  const int lane = (idx >> 3) & 63;
  const int wv   = (idx >> 9) & 3;
  const int fh   = idx >> 11;
  const int f    = fh % FRAGS_HALF;
  const int half = fh / FRAGS_HALF;
  const float* Wi0 = half ? dWih0 : eWih0;
  const float* Wi  = half ? dWih  : eWih;
  const float* Wh  = half ? dWhh  : eWhh;
  int l, q, kt;
  if (f < 12) { l = 0; q = f / 3; kt = f % 3; }
  else        { int ff = f - 12; l = 1 + ff / 16; ff %= 16; q = ff / 4; kt = ff % 4; }
  const int g    = q * 64 + wv * 16 + (lane & 15);
  const int k_in = ((lane >> 4) << 3) + j;
  float v;
  if (l == 0) {
    if (kt == 0) v = (k_in < NIN) ? Wi0[g * NIN + k_in] : 0.0f;
    else         v = Wh[g * H + (kt - 1) * 32 + k_in];
  } else {
    if (kt < 2) v = Wi[((l - 1) * 256 + g) * H + kt * 32 + k_in];
    else        v = Wh[(l * 256 + g) * H + (kt - 2) * 32 + k_in];
  }
  wq[idx] = (_Float16)v;
}

// ---------------------------------------------------------------------------
__device__ __forceinline__ float rcpf(float x) { return __builtin_amdgcn_rcpf(x); }
__device__ __forceinline__ f32x4 mf(h8 a, h8 b, f32x4 c) {
  return __builtin_amdgcn_mfma_f32_16x16x32_f16(a, b, c, 0, 0, 0);
}
#define SPLAT(v) ((f32x4){(v), (v), (v), (v)})

// merged-rcp LSTM cell: 5 exp + 3 rcp (+2 clamps); absmax-validated R6-R15.
__device__ __forceinline__ float ew_one(float gi, float gf, float gg, float go,
                                        float& c) {
  gg = fminf(fmaxf(gg, -20.0f), 20.0f);
  float eni = __expf(-gi);
  float e2g = __expf(2.0f * gg);
  float enf = __expf(-gf);
  float eno = __expf(-go);
  c = c * rcpf(1.0f + enf) + (e2g - 1.0f) * rcpf((1.0f + eni) * (e2g + 1.0f));
  float cc = fminf(fmaxf(c, -20.0f), 20.0f);
  float e2c = __expf(2.0f * cc);
  return (e2c - 1.0f) * rcpf((1.0f + eno) * (e2c + 1.0f));
}

// pair-ew: rows rb..rb+1 with f32x2 c-state (row order identical to cell_ew)
__device__ __forceinline__ void ew_pair(const f32x4& g0, const f32x4& g1,
                                        const f32x4& g2, const f32x4& g3,
                                        f32x2& c, _Float16* outbuf,
                                        int quad, int r16, int sl, int rb) {
  float cv0 = c[0];
  float h0 = ew_one(g0[rb], g1[rb], g2[rb], g3[rb], cv0);
  c[0] = cv0;
  outbuf[(quad * 4 + rb) * HPAD + sl * 16 + r16] = (_Float16)h0;
  float cv1 = c[1];
  float h1 = ew_one(g0[rb + 1], g1[rb + 1], g2[rb + 1], g3[rb + 1], cv1);
  c[1] = cv1;
  outbuf[(quad * 4 + rb + 1) * HPAD + sl * 16 + r16] = (_Float16)h1;
}

// prec (FMA order identical to R10 precH/prec0)
__device__ __forceinline__ void precc(const h8 (&w)[8], h8 ar0, h8 ar1,
                                      f32x4 b, f32x4 (&ac)[4]) {
  #pragma unroll
  for (int q = 0; q < 4; q++)
    ac[q] = mf(ar1, w[q * 2 + 1], mf(ar0, w[q * 2], SPLAT(b[q])));
}
__device__ __forceinline__ void readA(const _Float16* buf, int r16, int quad,
                                      h8& a0, h8& a1) {
  a0 = *(const h8*)(buf + r16 * HPAD + quad * 8);
  a1 = *(const h8*)(buf + r16 * HPAD + 32 + quad * 8);
}

// ===========================================================================
// ENCODER kernel: 128 blocks x 512 threads, BB=16.  (R10 verbatim.)
// ===========================================================================
__global__ void __launch_bounds__(512, 2)
lstm_enc(const float* __restrict__ X,
         const float* __restrict__ encb,
         const h8* __restrict__ WQ,
         _Float16* __restrict__ hG,
         float* __restrict__ cG) {
  __shared__ _Float16 Hb[NL][2][16][HPAD];   // 18432 B
  __shared__ _Float16 Xb[2][16][HPAD];       //  4608 B

  const int tid  = threadIdx.x;
  const int wv   = tid >> 6;        // 0..7
  const int lane = tid & 63;
  const int quad = lane >> 4;
  const int r16  = lane & 15;
  const int grp  = wv >> 2;         // col-half
  const int lw   = wv & 3;          // layer
  const int bbase = blockIdx.x * 16;

  {
    float* p = (float*)&Hb[0][0][0][0];
    for (int i = tid; i < 4608; i += 512) p[i] = 0.0f;
    float* px = (float*)&Xb[0][0][0];
    for (int i = tid; i < 1152; i += 512) px[i] = 0.0f;
  }
  if (tid < 16 * NIN) {
    int m = tid / NIN, ii = tid - m * NIN;
    Xb[0][m][ii] = (_Float16)X[((size_t)0 * BATCH + bbase + m) * NIN + ii];
  }

  // weights: 8 n-tiles {q*4 + 2*grp + cc}, 4 k-tiles each
  h8 we[8][4];
  #pragma unroll
  for (int q = 0; q < 4; q++)
    #pragma unroll
    for (int cc = 0; cc < 2; cc++)
      #pragma unroll
      for (int kt = 0; kt < 4; kt++)
        we[q * 2 + cc][kt] =
            WQ[(PACK_H8 + PROJ_H8) +
               ((lw * 64 + (q * 4 + 2 * grp + cc) * 4 + kt) * 64 + lane)];
  float ben[8];
  #pragma unroll
  for (int q = 0; q < 4; q++)
    #pragma unroll
    for (int cc = 0; cc < 2; cc++)
      ben[q * 2 + cc] = encb[lw * 256 + q * 64 + (2 * grp + cc) * 16 + r16];

  f32x4 ce[2];
  ce[0] = SPLAT(0.f); ce[1] = SPLAT(0.f);

  // 2-deep x prefetch: wave (lw=0, grp=0), lanes 0..47, 2 floats each
  const bool pfLane = (wv == 0) && (lane < 48);
  const int  pe0 = lane * 2, pe1 = pe0 + 1;
  const int  pm0 = pe0 / NIN, pc0 = pe0 % NIN;
  const int  pm1 = pe1 / NIN, pc1 = pe1 % NIN;
  float pf0 = 0.f, pf1 = 0.f;
  if (pfLane) {
    const float* xs = X + ((size_t)1 * BATCH + bbase) * NIN;
    pf0 = xs[pe0]; pf1 = xs[pe1];
  }

  __syncthreads();

  #pragma unroll 1
  for (int i = 0; i < S_LEN + NL - 1; i++) {     // 123 intervals
    const int p = i & 1;
    const bool active = (i >= lw) && (i - lw < S_LEN);
    if (active) {
      const _Float16* inb = (lw == 0) ? &Xb[p][0][0] : &Hb[lw - 1][p ^ 1][0][0];
      const _Float16* rcb = &Hb[lw][p ^ 1][0][0];
      h8 ai0 = *(const h8*)(inb + r16 * HPAD + quad * 8);
      h8 ai1 = {};
      if (lw) ai1 = *(const h8*)(inb + r16 * HPAD + 32 + quad * 8);
      h8 ar0 = *(const h8*)(rcb + r16 * HPAD + quad * 8);
      h8 ar1 = *(const h8*)(rcb + r16 * HPAD + 32 + quad * 8);

      float nf0 = 0.f, nf1 = 0.f;
      if (pfLane && (i + 2 < S_LEN)) {
        const float* xs = X + ((size_t)(i + 2) * BATCH + bbase) * NIN;
        nf0 = xs[pe0]; nf1 = xs[pe1];
      }

      f32x4 a[8];
      #pragma unroll
      for (int j = 0; j < 8; j++) {
        f32x4 t = SPLAT(ben[j]);
        t = mf(ai0, we[j][0], t);
        if (lw) t = mf(ai1, we[j][1], t);
        t = mf(ar0, we[j][2], t);
        t = mf(ar1, we[j][3], t);
        a[j] = t;
      }

      _Float16* wb = &Hb[lw][p][0][0];
      #pragma unroll
      for (int r = 0; r < 4; r++) {
        hh2 hv;
        #pragma unroll
        for (int cc = 0; cc < 2; cc++) {
          float cv = ce[cc][r];
          hv[cc] = (_Float16)ew_one(a[cc][r], a[2 + cc][r],
                                    a[4 + cc][r], a[6 + cc][r], cv);
          ce[cc][r] = cv;
        }
        // permuted layout: col c = ct*16+r16 lands at 4*r16+ct; ct = 2*grp+cc
        *(hh2*)(wb + (quad * 4 + r) * HPAD + 4 * r16 + 2 * grp) = hv;
      }

      if (pfLane && (i + 1 < S_LEN)) {
        Xb[p ^ 1][pm0][pc0] = (_Float16)pf0;
        Xb[p ^ 1][pm1][pc1] = (_Float16)pf1;
      }
      pf0 = nf0; pf1 = nf1;
    }
    bar_lgkm();
  }

  // ---- store c to global (per-lane direct) ----
  #pragma unroll
  for (int cc = 0; cc < 2; cc++)
    #pragma unroll
    for (int r = 0; r < 4; r++)
      cG[((size_t)lw * BATCH + bbase + quad * 4 + r) * H +
         (2 * grp + cc) * 16 + r16] = ce[cc][r];

  // ---- store final h (unpermute via PI) to global ----
  #pragma unroll
  for (int u = 0; u < 8; u++) {
    int i2 = tid + u * 512;
    int c = i2 & 63, m = (i2 >> 6) & 15, l = (i2 >> 10) & 3;
    hG[((size_t)l * BATCH + bbase + m) * H + c] =
        Hb[l][(l + 1) & 1][m][PI(c)];
  }
}

// ===========================================================================
// DECODER kernel: 128 blocks x 512 threads, 8 waves = 4 col-slices x {F,P}.
// 2 waves/SIMD. Duplicate-compute rebalance: both roles compute gate MFMAs
// (bit-identical); F ews rows {0,1} + proj/out; P ews rows {2,3} + prec/ACs.
// Barrier structure identical to R14 (1 per phase, 4 per step).
// ===========================================================================
__global__ void __launch_bounds__(512, 2)
lstm_dec(const float* __restrict__ X,
         const float* __restrict__ decb,
         const float* __restrict__ linb,
         const h8* __restrict__ WQ,
         const _Float16* __restrict__ hG,
         const float* __restrict__ cG,
         float* __restrict__ out) {
  __shared__ _Float16 Hb[NL][2][16][HPAD];   // 18432 B
  __shared__ f32x4 ACs[NL][4][4][64];        // 65536 B, [l][sl][j][lane]

  const int tid   = threadIdx.x;
  const int wv    = tid >> 6;        // 0..7
  const int sl    = wv & 3;          // col-slice
  const int roleP = wv >> 2;         // 0 = F (rows 0,1 + proj), 1 = P (rows 2,3 + prec)
  const int lane  = tid & 63;
  const int quad  = lane >> 4;
  const int r16   = lane & 15;
  const int bbase = blockIdx.x * 16;
  const int rb    = roleP ? 2 : 0;   // ew row base

  // load encoder-final h into Hb[l][1] (all 512 threads)
  #pragma unroll
  for (int u = 0; u < 8; u++) {
    int i2 = tid + u * 512;
    int l = i2 >> 10, m = (i2 >> 6) & 15, c = i2 & 63;
    Hb[l][1][m][c] = hG[((size_t)l * BATCH + bbase + m) * H + c];
  }
  __syncthreads();   // h-load visible

  // ---- fire weights (both roles) ----
  h8 wf0[4], wfH[3][8];
  #pragma unroll
  for (int q = 0; q < 4; q++)
    wf0[q] = WQ[((FRAGS_HALF + q * 3) * 4 + sl) * 64 + lane];
  #pragma unroll
  for (int l = 0; l < 3; l++)
    #pragma unroll
    for (int e = 0; e < 8; e++) {
      int q = e >> 1, k = e & 1;
      wfH[l][e] = WQ[((FRAGS_HALF + 12 + l * 16 + q * 4 + k) * 4 + sl) * 64 + lane];
    }

  // ---- proj frags + bias (both roles compute proj; only F stores out) ----
  h8 lwA0 = WQ[PACK_H8 + lane];
  h8 lwA1 = WQ[PACK_H8 + 64 + lane];
  f32x4 lbq;
  #pragma unroll
  for (int r = 0; r < 4; r++)
    lbq[r] = (quad * 4 + r < NIN) ? linb[quad * 4 + r] : 0.0f;

  // x[119] A-frag (both roles)
  h8 xseed = {};
  if (quad == 0) {
    const float* xs = X + ((size_t)(S_LEN - 1) * BATCH + bbase + r16) * NIN;
    #pragma unroll
    for (int j = 0; j < 6; j++) xseed[j] = (_Float16)xs[j];
  }

  // ---- c-state rows quad*4+rb+{0,1}, all 4 layers ----
  f32x2 c0, c1, c2, c3;
  #pragma unroll
  for (int j = 0; j < 2; j++) {
    c0[j] = cG[((size_t)0 * BATCH + bbase + quad * 4 + rb + j) * H + sl * 16 + r16];
    c1[j] = cG[((size_t)1 * BATCH + bbase + quad * 4 + rb + j) * H + sl * 16 + r16];
    c2[j] = cG[((size_t)2 * BATCH + bbase + quad * 4 + rb + j) * H + sl * 16 + r16];
    c3[j] = cG[((size_t)3 * BATCH + bbase + quad * 4 + rb + j) * H + sl * 16 + r16];
  }

  // ---- P-only: prec weights + biases + seed ----
  h8 wp0[8], wpH[3][8];
  f32x4 b0, b1, b2, b3;
  if (roleP) {
    #pragma unroll
    for (int e = 0; e < 8; e++) {
      int q = e >> 1, k = e & 1;
      wp0[e] = WQ[((FRAGS_HALF + q * 3 + 1 + k) * 4 + sl) * 64 + lane];
    }
    #pragma unroll
    for (int l = 0; l < 3; l++)
      #pragma unroll
      for (int e = 0; e < 8; e++) {
        int q = e >> 1, k = e & 1;
        wpH[l][e] = WQ[((FRAGS_HALF + 12 + l * 16 + q * 4 + 2 + k) * 4 + sl) * 64 + lane];
      }
    #pragma unroll
    for (int q = 0; q < 4; q++) {
      b0[q] = decb[0 * 256 + q * 64 + sl * 16 + r16];
      b1[q] = decb[1 * 256 + q * 64 + sl * 16 + r16];
      b2[q] = decb[2 * 256 + q * 64 + sl * 16 + r16];
      b3[q] = decb[3 * 256 + q * 64 + sl * 16 + r16];
    }
    // seed: prec layers 0,1,2 from encoder-final h
    h8 s0, s1;
    f32x4 a[4];
    readA(&Hb[0][1][0][0], r16, quad, s0, s1);
    precc(wp0, s0, s1, b0, a);
    #pragma unroll
    for (int j = 0; j < 4; j++) ACs[0][sl][j][lane] = a[j];
    readA(&Hb[1][1][0][0], r16, quad, s0, s1);
    precc(wpH[0], s0, s1, b1, a);
    #pragma unroll
    for (int j = 0; j < 4; j++) ACs[1][sl][j][lane] = a[j];
    readA(&Hb[2][1][0][0], r16, quad, s0, s1);
    precc(wpH[1], s0, s1, b2, a);
    #pragma unroll
    for (int j = 0; j < 4; j++) ACs[2][sl][j][lane] = a[j];
  }

  bar_lgkm();   // seed visible (one bar on both paths)

  #pragma unroll 1
  for (int t = 0; t < TLEN; t++) {
    const int cur = t & 1, prv = cur ^ 1;
    { // ---- phase A: proj(h3[t-1]) + layer-0 gates ; P: prec L3 ----
      h8 ar0, ar1;
      readA(&Hb[3][prv][0][0], r16, quad, ar0, ar1);
      if (roleP) {               // prec L3 (consumed in phase D this step)
        f32x4 a[4]; precc(wpH[2], ar0, ar1, b3, a);
        #pragma unroll
        for (int j = 0; j < 4; j++) ACs[3][sl][j][lane] = a[j];
      }
      h8 ax;
      if (t == 0) {
        ax = xseed;
      } else {
        f32x4 ap = lbq;
        ap = mf(lwA0, ar0, ap);   // identical on both roles -> identical ax
        ap = mf(lwA1, ar1, ap);
        if (!roleP && sl == 0) {
          #pragma unroll
          for (int r = 0; r < 4; r++) {
            const int fm = quad * 4 + r;
            if (fm < NIN)
              out[((size_t)(t - 1) * BATCH + bbase + r16) * NIN + fm] = ap[r];
          }
        }
        float x4 = swz16(ap[0]);
        float x5 = swz16(ap[1]);
        h8 xa = {};
        xa[0] = (_Float16)ap[0]; xa[1] = (_Float16)ap[1];
        xa[2] = (_Float16)ap[2]; xa[3] = (_Float16)ap[3];
        xa[4] = (_Float16)x4;    xa[5] = (_Float16)x5;
        h8 zz = {};
        ax = (quad == 0) ? xa : zz;
      }
      f32x4 g0 = mf(ax, wf0[0], ACs[0][sl][0][lane]);
      f32x4 g1 = mf(ax, wf0[1], ACs[0][sl][1][lane]);
      f32x4 g2 = mf(ax, wf0[2], ACs[0][sl][2][lane]);
      f32x4 g3 = mf(ax, wf0[3], ACs[0][sl][3][lane]);
      ew_pair(g0, g1, g2, g3, c0, &Hb[0][cur][0][0], quad, r16, sl, rb);
      bar_lgkm();
    }
    { // ---- phase B: layer-1 gates ; P: prec L0 ----
      h8 ai0, ai1;
      readA(&Hb[0][cur][0][0], r16, quad, ai0, ai1);
      if (roleP) {               // prec L0 (consumed next step phase A)
        f32x4 a[4]; precc(wp0, ai0, ai1, b0, a);
        #pragma unroll
        for (int j = 0; j < 4; j++) ACs[0][sl][j][lane] = a[j];
      }
      f32x4 g0 = mf(ai1, wfH[0][1], mf(ai0, wfH[0][0], ACs[1][sl][0][lane]));
      f32x4 g1 = mf(ai1, wfH[0][3], mf(ai0, wfH[0][2], ACs[1][sl][1][lane]));
      f32x4 g2 = mf(ai1, wfH[0][5], mf(ai0, wfH[0][4], ACs[1][sl][2][lane]));
      f32x4 g3 = mf(ai1, wfH[0][7], mf(ai0, wfH[0][6], ACs[1][sl][3][lane]));
      ew_pair(g0, g1, g2, g3, c1, &Hb[1][cur][0][0], quad, r16, sl, rb);
      bar_lgkm();
    }
    { // ---- phase C: layer-2 gates ; P: prec L1 ----
      h8 ai0, ai1;
      readA(&Hb[1][cur][0][0], r16, quad, ai0, ai1);
      if (roleP) {
        f32x4 a[4]; precc(wpH[0], ai0, ai1, b1, a);
        #pragma unroll
        for (int j = 0; j < 4; j++) ACs[1][sl][j][lane] = a[j];
      }
      f32x4 g0 = mf(ai1, wfH[1][1], mf(ai0, wfH[1][0], ACs[2][sl][0][lane]));
      f32x4 g1 = mf(ai1, wfH[1][3], mf(ai0, wfH[1][2], ACs[2][sl][1][lane]));
      f32x4 g2 = mf(ai1, wfH[1][5], mf(ai0, wfH[1][4], ACs[2][sl][2][lane]));
      f32x4 g3 = mf(ai1, wfH[1][7], mf(ai0, wfH[1][6], ACs[2][sl][3][lane]));
      ew_pair(g0, g1, g2, g3, c2, &Hb[2][cur][0][0], quad, r16, sl, rb);
      bar_lgkm();
    }
    { // ---- phase D: layer-3 gates ; P: prec L2 ----
      h8 ai0, ai1;
      readA(&Hb[2][cur][0][0], r16, quad, ai0, ai1);
      if (roleP) {
        f32x4 a[4]; precc(wpH[1], ai0, ai1, b2, a);
        #pragma unroll
        for (int j = 0; j < 4; j++) ACs[2][sl][j][lane] = a[j];
      }
      f32x4 g0 = mf(ai1, wfH[2][1], mf(ai0, wfH[2][0], ACs[3][sl][0][lane]));
      f32x4 g1 = mf(ai1, wfH[2][3], mf(ai0, wfH[2][2], ACs[3][sl][1][lane]));
      f32x4 g2 = mf(ai1, wfH[2][5], mf(ai0, wfH[2][4], ACs[3][sl][2][lane]));
      f32x4 g3 = mf(ai1, wfH[2][7], mf(ai0, wfH[2][6], ACs[3][sl][3][lane]));
      ew_pair(g0, g1, g2, g3, c3, &Hb[3][cur][0][0], quad, r16, sl, rb);
      bar_lgkm();
    }
  }

  // epilogue: out[TLEN-1] from h3 of last step (parity 1)
  if (!roleP && sl == 0) {
    h8 ar0, ar1;
    readA(&Hb[3][1][0][0], r16, quad, ar0, ar1);
    f32x4 ap = lbq;
    ap = mf(lwA0, ar0, ap);
    ap = mf(lwA1, ar1, ap);
    #pragma unroll
    for (int r = 0; r < 4; r++) {
      const int fm = quad * 4 + r;
      if (fm < NIN)
        out[((size_t)(TLEN - 1) * BATCH + bbase + r16) * NIN + fm] = ap[r];
    }
  }
}

// ---------------------------------------------------------------------------
extern "C" void kernel_launch(void* const* d_in, const int* in_sizes, int n_in,
                              void* d_out, int out_size, void* d_ws, size_t ws_size,
                              hipStream_t stream) {
  const float* X     = (const float*)d_in[0];
  const float* eWih0 = (const float*)d_in[1];
  const float* eWih  = (const float*)d_in[2];
  const float* eWhh  = (const float*)d_in[3];
  const float* eb    = (const float*)d_in[4];
  const float* dWih0 = (const float*)d_in[5];
  const float* dWih  = (const float*)d_in[6];
  const float* dWhh  = (const float*)d_in[7];
  const float* db    = (const float*)d_in[8];
  const float* lW    = (const float*)d_in[9];
  const float* lb    = (const float*)d_in[10];

  _Float16* wq = (_Float16*)d_ws;
  _Float16* hG = (_Float16*)((char*)d_ws + WS_HOFF);
  float*    cG = (float*)((char*)d_ws + WS_COFF);

  prep_weights<<<(NTOT + 255) / 256, 256, 0, stream>>>(
      eWih0, eWih, eWhh, dWih0, dWih, dWhh, lW, wq);

  lstm_enc<<<BATCH / 16, 512, 0, stream>>>(
      X, eb, (const h8*)wq, hG, cG);

  lstm_dec<<<BATCH / 16, 512, 0, stream>>>(
      X, db, lb, (const h8*)wq, hG, cG, (float*)d_out);
}

// Round 7
// 526.985 us; speedup vs baseline: 1.8635x; 1.8635x over previous
//
#include <hip/hip_runtime.h>

// ---------------------------------------------------------------------------
// Round 17: decoder reverted to R14 verbatim (best: dec 260us; R15 mid-barrier
//   +380cy each, R16 duplicate-weights spilled to scratch -> both regressed).
//   Encoder: wave->SIMD decorrelation only. Old map lw=wv&3,grp=wv>>2 puts the
//   SAME layer's two col-halves on one SIMD (identical streams, synchronized
//   trans bursts + stalls). New map lw=(wv>>1)&3, grp=wv&1 pairs layers
//   (l, l+2) per SIMD -> phase-shifted bursts fill each other's gaps.
//   Pure renaming; bit-identical math. absmax canary: 4.8828e-4.
// ---------------------------------------------------------------------------

#define S_LEN 120
#define BATCH 2048
#define NIN   6
#define H     64
#define NL    4
#define TLEN  120

#define HPAD 72            // row stride in halves (144 B)

#define FRAGS_HALF 60      // col-sliced: 12 (layer0) + 3*16
#define PACK_H8    (2 * FRAGS_HALF * 4 * 64)
#define PROJ_H8    (2 * 64)
#define NPACK      ((PACK_H8 + PROJ_H8) * 8)   // 246784 fp16 elements
#define EPACK_EL   (256 * 64 * 8)              // encoder pipeline pack
#define NTOT       (NPACK + EPACK_EL)          // 377856 (~756 KB)

// workspace byte offsets (after the weight pack)
#define WS_HOFF (768 * 1024)                   // h: 4*2048*64 fp16 = 1 MB
#define WS_COFF (WS_HOFF + 1024 * 1024)        // c: 4*2048*64 f32 = 2 MB

#define PERM(kk) ((((kk) & 3) << 4) | ((kk) >> 2))   // pi^-1
#define PI(c)    ((((c) & 15) << 2) | ((c) >> 4))    // pi

typedef _Float16 h8    __attribute__((ext_vector_type(8)));
typedef _Float16 hh2   __attribute__((ext_vector_type(2)));
typedef float    f32x4 __attribute__((ext_vector_type(4)));

__device__ __forceinline__ void bar_lgkm() {
  asm volatile("s_waitcnt lgkmcnt(0)\n\ts_barrier" ::: "memory");
}

// lane L <-> lane L^16 exchange (BitMode xor=16, and=0x1F)
__device__ __forceinline__ float swz16(float v) {
  int i = __builtin_bit_cast(int, v);
  i = __builtin_amdgcn_ds_swizzle(i, 0x401F);
  return __builtin_bit_cast(float, i);
}

// ---------------------------------------------------------------------------
// Weight pack (identical to rounds 5-16).
// ---------------------------------------------------------------------------
__global__ void prep_weights(const float* __restrict__ eWih0,
                             const float* __restrict__ eWih,
                             const float* __restrict__ eWhh,
                             const float* __restrict__ dWih0,
                             const float* __restrict__ dWih,
                             const float* __restrict__ dWhh,
                             const float* __restrict__ linW,
                             _Float16* __restrict__ wq) {
  int idx = blockIdx.x * blockDim.x + threadIdx.x;
  if (idx >= NTOT) return;

  if (idx >= NPACK) {                      // ---- encoder pipeline pack ----
    int p    = idx - NPACK;
    int j    = p & 7;
    int lane = (p >> 3) & 63;
    int fe   = p >> 9;
    int kt   = fe & 3, nt = (fe >> 2) & 15, l = fe >> 6;
    int g    = nt * 16 + (lane & 15);
    int koff = ((lane >> 4) << 3) + j;
    float v = 0.0f;
    if (l == 0) {
      if (kt == 0)      v = (koff < NIN) ? eWih0[g * NIN + koff] : 0.0f;
      else if (kt == 1) v = 0.0f;
      else { int kk = (kt - 2) * 32 + koff; v = eWhh[g * H + PERM(kk)]; }
    } else {
      if (kt < 2) { int kk = kt * 32 + koff;
                    v = eWih[((l - 1) * 256 + g) * H + PERM(kk)]; }
      else        { int kk = (kt - 2) * 32 + koff;
                    v = eWhh[(l * 256 + g) * H + PERM(kk)]; }
    }
    wq[idx] = (_Float16)v;
    return;
  }

  if (idx >= PACK_H8 * 8) {                // ---- linW A-layout frags ----
    int p    = idx - PACK_H8 * 8;
    int j    = p & 7;
    int lane = (p >> 3) & 63;
    int fr   = p >> 9;
    int m    = lane & 15;
    int k    = fr * 32 + ((lane >> 4) << 3) + j;
    wq[idx] = (_Float16)((m < NIN) ? linW[m * H + k] : 0.0f);
    return;
  }

  // ---- col-sliced pack (decoder uses dec half) ----
  const int j    = idx & 7;
  const int lane = (idx >> 3) & 63;
  const int wv   = (idx >> 9) & 3;
  const int fh   = idx >> 11;
  const int f    = fh % FRAGS_HALF;
  const int half = fh / FRAGS_HALF;
  const float* Wi0 = half ? dWih0 : eWih0;
  const float* Wi  = half ? dWih  : eWih;
  const float* Wh  = half ? dWhh  : eWhh;
  int l, q, kt;
  if (f < 12) { l = 0; q = f / 3; kt = f % 3; }
  else        { int ff = f - 12; l = 1 + ff / 16; ff %= 16; q = ff / 4; kt = ff % 4; }
  const int g    = q * 64 + wv * 16 + (lane & 15);
  const int k_in = ((lane >> 4) << 3) + j;
  float v;
  if (l == 0) {
    if (kt == 0) v = (k_in < NIN) ? Wi0[g * NIN + k_in] : 0.0f;
    else         v = Wh[g * H + (kt - 1) * 32 + k_in];
  } else {
    if (kt < 2) v = Wi[((l - 1) * 256 + g) * H + kt * 32 + k_in];
    else        v = Wh[(l * 256 + g) * H + (kt - 2) * 32 + k_in];
  }
  wq[idx] = (_Float16)v;
}

// ---------------------------------------------------------------------------
__device__ __forceinline__ float rcpf(float x) { return __builtin_amdgcn_rcpf(x); }
__device__ __forceinline__ f32x4 mf(h8 a, h8 b, f32x4 c) {
  return __builtin_amdgcn_mfma_f32_16x16x32_f16(a, b, c, 0, 0, 0);
}
#define SPLAT(v) ((f32x4){(v), (v), (v), (v)})

// merged-rcp LSTM cell: 5 exp + 3 rcp (+2 clamps); absmax-validated R6-R16.
__device__ __forceinline__ float ew_one(float gi, float gf, float gg, float go,
                                        float& c) {
  gg = fminf(fmaxf(gg, -20.0f), 20.0f);
  float eni = __expf(-gi);
  float e2g = __expf(2.0f * gg);
  float enf = __expf(-gf);
  float eno = __expf(-go);
  c = c * rcpf(1.0f + enf) + (e2g - 1.0f) * rcpf((1.0f + eni) * (e2g + 1.0f));
  float cc = fminf(fmaxf(c, -20.0f), 20.0f);
  float e2c = __expf(2.0f * cc);
  return (e2c - 1.0f) * rcpf((1.0f + eno) * (e2c + 1.0f));
}

__device__ __forceinline__ void cell_ew(f32x4 g0, f32x4 g1, f32x4 g2, f32x4 g3,
                                        f32x4& c, _Float16* outbuf,
                                        int quad, int r16, int sl) {
  #pragma unroll
  for (int r = 0; r < 4; r++) {
    float cv = c[r];
    float hv = ew_one(g0[r], g1[r], g2[r], g3[r], cv);
    c[r] = cv;
    outbuf[(quad * 4 + r) * HPAD + sl * 16 + r16] = (_Float16)hv;
  }
}

// compact role-split helpers (FMA order identical to R10 fireH/precH/fire0/prec0)
__device__ __forceinline__ void precc(const h8 (&w)[8], h8 ar0, h8 ar1,
                                      f32x4 b, f32x4 (&ac)[4]) {
  #pragma unroll
  for (int q = 0; q < 4; q++)
    ac[q] = mf(ar1, w[q * 2 + 1], mf(ar0, w[q * 2], SPLAT(b[q])));
}
__device__ __forceinline__ void fireHc(const h8 (&w)[8], h8 ai0, h8 ai1,
                                       const f32x4 (&ac)[4], f32x4& c,
                                       _Float16* outbuf, int quad, int r16, int sl) {
  f32x4 g0 = mf(ai1, w[1], mf(ai0, w[0], ac[0]));
  f32x4 g1 = mf(ai1, w[3], mf(ai0, w[2], ac[1]));
  f32x4 g2 = mf(ai1, w[5], mf(ai0, w[4], ac[2]));
  f32x4 g3 = mf(ai1, w[7], mf(ai0, w[6], ac[3]));
  cell_ew(g0, g1, g2, g3, c, outbuf, quad, r16, sl);
}
__device__ __forceinline__ void fire0c(const h8 (&w)[4], h8 ax,
                                       const f32x4 (&ac)[4], f32x4& c,
                                       _Float16* outbuf, int quad, int r16, int sl) {
  f32x4 g0 = mf(ax, w[0], ac[0]);
  f32x4 g1 = mf(ax, w[1], ac[1]);
  f32x4 g2 = mf(ax, w[2], ac[2]);
  f32x4 g3 = mf(ax, w[3], ac[3]);
  cell_ew(g0, g1, g2, g3, c, outbuf, quad, r16, sl);
}
__device__ __forceinline__ void readA(const _Float16* buf, int r16, int quad,
                                      h8& a0, h8& a1) {
  a0 = *(const h8*)(buf + r16 * HPAD + quad * 8);
  a1 = *(const h8*)(buf + r16 * HPAD + 32 + quad * 8);
}

// ===========================================================================
// ENCODER kernel: 128 blocks x 512 threads, BB=16.
// R17: wave map lw=(wv>>1)&3, grp=wv&1 -> each SIMD hosts layers (l, l+2)
// instead of one layer's two halves. Everything else R10-identical.
// ===========================================================================
__global__ void __launch_bounds__(512, 2)
lstm_enc(const float* __restrict__ X,
         const float* __restrict__ encb,
         const h8* __restrict__ WQ,
         _Float16* __restrict__ hG,
         float* __restrict__ cG) {
  __shared__ _Float16 Hb[NL][2][16][HPAD];   // 18432 B
  __shared__ _Float16 Xb[2][16][HPAD];       //  4608 B

  const int tid  = threadIdx.x;
  const int wv   = tid >> 6;        // 0..7
  const int lane = tid & 63;
  const int quad = lane >> 4;
  const int r16  = lane & 15;
  const int grp  = wv & 1;          // col-half          (R17: was wv>>2)
  const int lw   = (wv >> 1) & 3;   // layer             (R17: was wv&3)
  const int bbase = blockIdx.x * 16;

  {
    float* p = (float*)&Hb[0][0][0][0];
    for (int i = tid; i < 4608; i += 512) p[i] = 0.0f;
    float* px = (float*)&Xb[0][0][0];
    for (int i = tid; i < 1152; i += 512) px[i] = 0.0f;
  }
  if (tid < 16 * NIN) {
    int m = tid / NIN, ii = tid - m * NIN;
    Xb[0][m][ii] = (_Float16)X[((size_t)0 * BATCH + bbase + m) * NIN + ii];
  }

  // weights: 8 n-tiles {q*4 + 2*grp + cc}, 4 k-tiles each
  h8 we[8][4];
  #pragma unroll
  for (int q = 0; q < 4; q++)
    #pragma unroll
    for (int cc = 0; cc < 2; cc++)
      #pragma unroll
      for (int kt = 0; kt < 4; kt++)
        we[q * 2 + cc][kt] =
            WQ[(PACK_H8 + PROJ_H8) +
               ((lw * 64 + (q * 4 + 2 * grp + cc) * 4 + kt) * 64 + lane)];
  float ben[8];
  #pragma unroll
  for (int q = 0; q < 4; q++)
    #pragma unroll
    for (int cc = 0; cc < 2; cc++)
      ben[q * 2 + cc] = encb[lw * 256 + q * 64 + (2 * grp + cc) * 16 + r16];

  f32x4 ce[2];
  ce[0] = SPLAT(0.f); ce[1] = SPLAT(0.f);

  // 2-deep x prefetch: wave (lw=0, grp=0) = wv 0, lanes 0..47, 2 floats each
  const bool pfLane = (wv == 0) && (lane < 48);
  const int  pe0 = lane * 2, pe1 = pe0 + 1;
  const int  pm0 = pe0 / NIN, pc0 = pe0 % NIN;
  const int  pm1 = pe1 / NIN, pc1 = pe1 % NIN;
  float pf0 = 0.f, pf1 = 0.f;
  if (pfLane) {
    const float* xs = X + ((size_t)1 * BATCH + bbase) * NIN;
    pf0 = xs[pe0]; pf1 = xs[pe1];
  }

  __syncthreads();

  #pragma unroll 1
  for (int i = 0; i < S_LEN + NL - 1; i++) {     // 123 intervals
    const int p = i & 1;
    const bool active = (i >= lw) && (i - lw < S_LEN);
    if (active) {
      const _Float16* inb = (lw == 0) ? &Xb[p][0][0] : &Hb[lw - 1][p ^ 1][0][0];
      const _Float16* rcb = &Hb[lw][p ^ 1][0][0];
      h8 ai0 = *(const h8*)(inb + r16 * HPAD + quad * 8);
      h8 ai1 = {};
      if (lw) ai1 = *(const h8*)(inb + r16 * HPAD + 32 + quad * 8);
      h8 ar0 = *(const h8*)(rcb + r16 * HPAD + quad * 8);
      h8 ar1 = *(const h8*)(rcb + r16 * HPAD + 32 + quad * 8);

      float nf0 = 0.f, nf1 = 0.f;
      if (pfLane && (i + 2 < S_LEN)) {
        const float* xs = X + ((size_t)(i + 2) * BATCH + bbase) * NIN;
        nf0 = xs[pe0]; nf1 = xs[pe1];
      }

      f32x4 a[8];
      #pragma unroll
      for (int j = 0; j < 8; j++) {
        f32x4 t = SPLAT(ben[j]);
        t = mf(ai0, we[j][0], t);
        if (lw) t = mf(ai1, we[j][1], t);
        t = mf(ar0, we[j][2], t);
        t = mf(ar1, we[j][3], t);
        a[j] = t;
      }

      _Float16* wb = &Hb[lw][p][0][0];
      #pragma unroll
      for (int r = 0; r < 4; r++) {
        hh2 hv;
        #pragma unroll
        for (int cc = 0; cc < 2; cc++) {
          float cv = ce[cc][r];
          hv[cc] = (_Float16)ew_one(a[cc][r], a[2 + cc][r],
                                    a[4 + cc][r], a[6 + cc][r], cv);
          ce[cc][r] = cv;
        }
        // permuted layout: col c = ct*16+r16 lands at 4*r16+ct; ct = 2*grp+cc
        *(hh2*)(wb + (quad * 4 + r) * HPAD + 4 * r16 + 2 * grp) = hv;
      }

      if (pfLane && (i + 1 < S_LEN)) {
        Xb[p ^ 1][pm0][pc0] = (_Float16)pf0;
        Xb[p ^ 1][pm1][pc1] = (_Float16)pf1;
      }
      pf0 = nf0; pf1 = nf1;
    }
    bar_lgkm();
  }

  // ---- store c to global (per-lane direct) ----
  #pragma unroll
  for (int cc = 0; cc < 2; cc++)
    #pragma unroll
    for (int r = 0; r < 4; r++)
      cG[((size_t)lw * BATCH + bbase + quad * 4 + r) * H +
         (2 * grp + cc) * 16 + r16] = ce[cc][r];

  // ---- store final h (unpermute via PI) to global ----
  #pragma unroll
  for (int u = 0; u < 8; u++) {
    int i2 = tid + u * 512;
    int c = i2 & 63, m = (i2 >> 6) & 15, l = (i2 >> 10) & 3;
    hG[((size_t)l * BATCH + bbase + m) * H + c] =
        Hb[l][(l + 1) & 1][m][PI(c)];
  }
}

// ===========================================================================
// DECODER kernel: R14 verbatim. 128 blocks x 512 threads, 8 waves =
// 4 col-slices x {F,P}. 2 waves/SIMD. Lane-contiguous AC handoff.
// F-waves at s_setprio(1); xa build via ds_swizzle xor-16.
// ===========================================================================
__global__ void __launch_bounds__(512, 2)
lstm_dec(const float* __restrict__ X,
         const float* __restrict__ decb,
         const float* __restrict__ linb,
         const h8* __restrict__ WQ,
         const _Float16* __restrict__ hG,
         const float* __restrict__ cG,
         float* __restrict__ out) {
  __shared__ _Float16 Hb[NL][2][16][HPAD];   // 18432 B
  __shared__ f32x4 ACs[NL][4][4][64];        // 65536 B, [l][sl][j][lane]

  const int tid   = threadIdx.x;
  const int wv    = tid >> 6;        // 0..7
  const int sl    = wv & 3;          // col-slice
  const int roleP = wv >> 2;         // 0 = fire wave, 1 = prec wave
  const int lane  = tid & 63;
  const int quad  = lane >> 4;
  const int r16   = lane & 15;
  const int bbase = blockIdx.x * 16;

  // load encoder-final h into Hb[l][1] (all 512 threads)
  #pragma unroll
  for (int u = 0; u < 8; u++) {
    int i2 = tid + u * 512;
    int l = i2 >> 10, m = (i2 >> 6) & 15, c = i2 & 63;
    Hb[l][1][m][c] = hG[((size_t)l * BATCH + bbase + m) * H + c];
  }
  __syncthreads();   // h-load visible

  if (roleP) {
    // ================= P wave: recurrent precompute =================
    h8 wp0[8], wpH[3][8];
    #pragma unroll
    for (int e = 0; e < 8; e++) {
      int q = e >> 1, k = e & 1;
      wp0[e] = WQ[((FRAGS_HALF + q * 3 + 1 + k) * 4 + sl) * 64 + lane];
    }
    #pragma unroll
    for (int l = 0; l < 3; l++)
      #pragma unroll
      for (int e = 0; e < 8; e++) {
        int q = e >> 1, k = e & 1;
        wpH[l][e] = WQ[((FRAGS_HALF + 12 + l * 16 + q * 4 + 2 + k) * 4 + sl) * 64 + lane];
      }
    f32x4 b0, b1, b2, b3;
    #pragma unroll
    for (int q = 0; q < 4; q++) {
      b0[q] = decb[0 * 256 + q * 64 + sl * 16 + r16];
      b1[q] = decb[1 * 256 + q * 64 + sl * 16 + r16];
      b2[q] = decb[2 * 256 + q * 64 + sl * 16 + r16];
      b3[q] = decb[3 * 256 + q * 64 + sl * 16 + r16];
    }

    // seed: prec layers 0,1,2 from encoder-final h
    {
      h8 s0, s1;
      f32x4 a[4];
      readA(&Hb[0][1][0][0], r16, quad, s0, s1);
      precc(wp0, s0, s1, b0, a);
      #pragma unroll
      for (int j = 0; j < 4; j++) ACs[0][sl][j][lane] = a[j];
      readA(&Hb[1][1][0][0], r16, quad, s0, s1);
      precc(wpH[0], s0, s1, b1, a);
      #pragma unroll
      for (int j = 0; j < 4; j++) ACs[1][sl][j][lane] = a[j];
      readA(&Hb[2][1][0][0], r16, quad, s0, s1);
      precc(wpH[1], s0, s1, b2, a);
      #pragma unroll
      for (int j = 0; j < 4; j++) ACs[2][sl][j][lane] = a[j];
    }
    bar_lgkm();   // matches F's pre-loop bar

    #pragma unroll 1
    for (int t = 0; t < TLEN; t++) {
      const int cur = t & 1, prv = cur ^ 1;
      { // ---- A: prec layer3 from h3[prv] ----
        h8 a0, a1; readA(&Hb[3][prv][0][0], r16, quad, a0, a1);
        f32x4 a[4]; precc(wpH[2], a0, a1, b3, a);
        #pragma unroll
        for (int j = 0; j < 4; j++) ACs[3][sl][j][lane] = a[j];
        bar_lgkm();
      }
      { // ---- B: prec layer0 from h0[cur] ----
        h8 a0, a1; readA(&Hb[0][cur][0][0], r16, quad, a0, a1);
        f32x4 a[4]; precc(wp0, a0, a1, b0, a);
        #pragma unroll
        for (int j = 0; j < 4; j++) ACs[0][sl][j][lane] = a[j];
        bar_lgkm();
      }
      { // ---- C: prec layer1 from h1[cur] ----
        h8 a0, a1; readA(&Hb[1][cur][0][0], r16, quad, a0, a1);
        f32x4 a[4]; precc(wpH[0], a0, a1, b1, a);
        #pragma unroll
        for (int j = 0; j < 4; j++) ACs[1][sl][j][lane] = a[j];
        bar_lgkm();
      }
      { // ---- D: prec layer2 from h2[cur] ----
        h8 a0, a1; readA(&Hb[2][cur][0][0], r16, quad, a0, a1);
        f32x4 a[4]; precc(wpH[1], a0, a1, b2, a);
        #pragma unroll
        for (int j = 0; j < 4; j++) ACs[2][sl][j][lane] = a[j];
        bar_lgkm();
      }
    }
  } else {
    // ================= F wave: fire + ew + proj (setprio 1) =================
    h8 wf0[4], wfH[3][8];
    #pragma unroll
    for (int q = 0; q < 4; q++)
      wf0[q] = WQ[((FRAGS_HALF + q * 3) * 4 + sl) * 64 + lane];
    #pragma unroll
    for (int l = 0; l < 3; l++)
      #pragma unroll
      for (int e = 0; e < 8; e++) {
        int q = e >> 1, k = e & 1;
        wfH[l][e] = WQ[((FRAGS_HALF + 12 + l * 16 + q * 4 + k) * 4 + sl) * 64 + lane];
      }

    // c slices
    f32x4 cs0, cs1, cs2, cs3;
    #pragma unroll
    for (int r = 0; r < 4; r++) {
      cs0[r] = cG[((size_t)0 * BATCH + bbase + quad * 4 + r) * H + sl * 16 + r16];
      cs1[r] = cG[((size_t)1 * BATCH + bbase + quad * 4 + r) * H + sl * 16 + r16];
      cs2[r] = cG[((size_t)2 * BATCH + bbase + quad * 4 + r) * H + sl * 16 + r16];
      cs3[r] = cG[((size_t)3 * BATCH + bbase + quad * 4 + r) * H + sl * 16 + r16];
    }

    h8 lwA0 = WQ[PACK_H8 + lane];
    h8 lwA1 = WQ[PACK_H8 + 64 + lane];
    f32x4 lbq;
    #pragma unroll
    for (int r = 0; r < 4; r++)
      lbq[r] = (quad * 4 + r < NIN) ? linb[quad * 4 + r] : 0.0f;

    // x[119] A-frag (k = quad*8+j; only k<6 real)
    h8 xseed = {};
    if (quad == 0) {
      const float* xs = X + ((size_t)(S_LEN - 1) * BATCH + bbase + r16) * NIN;
      #pragma unroll
      for (int j = 0; j < 6; j++) xseed[j] = (_Float16)xs[j];
    }

    bar_lgkm();   // matches P's seed bar

    __builtin_amdgcn_s_setprio(1);   // F gates every barrier; bias issue to it

    #pragma unroll 1
    for (int t = 0; t < TLEN; t++) {
      const int cur = t & 1, prv = cur ^ 1;
      { // ---- A: proj(h3[t-1]) + layer-0 fire ----
        h8 ar0, ar1;
        readA(&Hb[3][prv][0][0], r16, quad, ar0, ar1);
        h8 ax;
        if (t == 0) {
          ax = xseed;
        } else {
          f32x4 ap = lbq;
          ap = mf(lwA0, ar0, ap);     // A = linW (m=feature), B = h3 (n=batch)
          ap = mf(lwA1, ar1, ap);
          if (sl == 0) {
            #pragma unroll
            for (int r = 0; r < 4; r++) {
              const int fm = quad * 4 + r;
              if (fm < NIN)
                out[((size_t)(t - 1) * BATCH + bbase + r16) * NIN + fm] = ap[r];
            }
          }
          // xa consumers are quad==0 lanes: shfl(ap[r], r16) is identity there;
          // feats 4,5 come from quad1 = lane^16 -> ds_swizzle xor-16.
          float x4 = swz16(ap[0]);
          float x5 = swz16(ap[1]);
          h8 xa = {};
          xa[0] = (_Float16)ap[0]; xa[1] = (_Float16)ap[1];
          xa[2] = (_Float16)ap[2]; xa[3] = (_Float16)ap[3];
          xa[4] = (_Float16)x4;    xa[5] = (_Float16)x5;
          h8 zz = {};
          ax = (quad == 0) ? xa : zz;
        }
        f32x4 ac[4];
        #pragma unroll
        for (int j = 0; j < 4; j++) ac[j] = ACs[0][sl][j][lane];
        fire0c(wf0, ax, ac, cs0, &Hb[0][cur][0][0], quad, r16, sl);
        bar_lgkm();
      }
      { // ---- B: fire layer1 ----
        h8 ai0, ai1;
        readA(&Hb[0][cur][0][0], r16, quad, ai0, ai1);
        f32x4 ac[4];
        #pragma unroll
        for (int j = 0; j < 4; j++) ac[j] = ACs[1][sl][j][lane];
        fireHc(wfH[0], ai0, ai1, ac, cs1, &Hb[1][cur][0][0], quad, r16, sl);
        bar_lgkm();
      }
      { // ---- C: fire layer2 ----
        h8 ai0, ai1;
        readA(&Hb[1][cur][0][0], r16, quad, ai0, ai1);
        f32x4 ac[4];
        #pragma unroll
        for (int j = 0; j < 4; j++) ac[j] = ACs[2][sl][j][lane];
        fireHc(wfH[1], ai0, ai1, ac, cs2, &Hb[2][cur][0][0], quad, r16, sl);
        bar_lgkm();
      }
      { // ---- D: fire layer3 ----
        h8 ai0, ai1;
        readA(&Hb[2][cur][0][0], r16, quad, ai0, ai1);
        f32x4 ac[4];
        #pragma unroll
        for (int j = 0; j < 4; j++) ac[j] = ACs[3][sl][j][lane];
        fireHc(wfH[2], ai0, ai1, ac, cs3, &Hb[3][cur][0][0], quad, r16, sl);
        bar_lgkm();
      }
    }

    __builtin_amdgcn_s_setprio(0);

    // epilogue: out[TLEN-1] from h3 of last step (parity 1)
    if (sl == 0) {
      h8 ar0, ar1;
      readA(&Hb[3][1][0][0], r16, quad, ar0, ar1);
      f32x4 ap = lbq;
      ap = mf(lwA0, ar0, ap);
      ap = mf(lwA1, ar1, ap);
      #pragma unroll
      for (int r = 0; r < 4; r++) {
        const int fm = quad * 4 + r;
        if (fm < NIN)
          out[((size_t)(TLEN - 1) * BATCH + bbase + r16) * NIN + fm] = ap[r];
      }
    }
  }
}

// ---------------------------------------------------------------------------
extern "C" void kernel_launch(void* const* d_in, const int* in_sizes, int n_in,
                              void* d_out, int out_size, void* d_ws, size_t ws_size,
                              hipStream_t stream) {
  const float* X     = (const float*)d_in[0];
  const float* eWih0 = (const float*)d_in[1];
  const float* eWih  = (const float*)d_in[2];
  const float* eWhh  = (const float*)d_in[3];
  const float* eb    = (const float*)d_in[4];
  const float* dWih0 = (const float*)d_in[5];
  const float* dWih  = (const float*)d_in[6];
  const float* dWhh  = (const float*)d_in[7];
  const float* db    = (const float*)d_in[8];
  const float* lW    = (const float*)d_in[9];
  const float* lb    = (const float*)d_in[10];

  _Float16* wq = (_Float16*)d_ws;
  _Float16* hG = (_Float16*)((char*)d_ws + WS_HOFF);
  float*    cG = (float*)((char*)d_ws + WS_COFF);

  prep_weights<<<(NTOT + 255) / 256, 256, 0, stream>>>(
      eWih0, eWih, eWhh, dWih0, dWih, dWhh, lW, wq);

  lstm_enc<<<BATCH / 16, 512, 0, stream>>>(
      X, eb, (const h8*)wq, hG, cG);

  lstm_dec<<<BATCH / 16, 512, 0, stream>>>(
      X, db, lb, (const h8*)wq, hG, cG, (float*)d_out);
}

// Round 8
// 488.982 us; speedup vs baseline: 2.0084x; 1.0777x over previous
//
#include <hip/hip_runtime.h>

// ---------------------------------------------------------------------------
// Round 18: log2e-folded gate weights + raw exp2 in the cell.
//   Gate rows (i,f,o) pre-scaled by -log2e, (g) by +2*log2e at pack time
//   (biases likewise at load). ew uses v_exp_f32 directly (2^x), removing
//   4 dependent v_mul per ew_one. Only exp(2c) keeps its runtime mul.
//   Structure frozen at R17 (best: 527.0 us): enc layer-paired SIMD map,
//   dec R14 F/P split + setprio + swz16. absmax moves off the 4.88e-4
//   canary (fp16 re-rounding of scaled weights) -- expected O(1e-3) pass.
// ---------------------------------------------------------------------------

#define S_LEN 120
#define BATCH 2048
#define NIN   6
#define H     64
#define NL    4
#define TLEN  120

#define HPAD 72            // row stride in halves (144 B)

#define FRAGS_HALF 60      // col-sliced: 12 (layer0) + 3*16
#define PACK_H8    (2 * FRAGS_HALF * 4 * 64)
#define PROJ_H8    (2 * 64)
#define NPACK      ((PACK_H8 + PROJ_H8) * 8)   // 246784 fp16 elements
#define EPACK_EL   (256 * 64 * 8)              // encoder pipeline pack
#define NTOT       (NPACK + EPACK_EL)          // 377856 (~756 KB)

// workspace byte offsets (after the weight pack)
#define WS_HOFF (768 * 1024)                   // h: 4*2048*64 fp16 = 1 MB
#define WS_COFF (WS_HOFF + 1024 * 1024)        // c: 4*2048*64 f32 = 2 MB

#define PERM(kk) ((((kk) & 3) << 4) | ((kk) >> 2))   // pi^-1
#define PI(c)    ((((c) & 15) << 2) | ((c) >> 4))    // pi

// gate scale factors: i,f,o -> -log2e ; g -> +2*log2e
#define SNEG (-1.44269504088896341f)
#define SGG  ( 2.88539008177792681f)
#define GGCLAMP 57.7078016355585362f           // 20 * 2*log2e
#define C2L2E 2.88539008177792681f             // 2*log2e for exp(2c)

typedef _Float16 h8    __attribute__((ext_vector_type(8)));
typedef _Float16 hh2   __attribute__((ext_vector_type(2)));
typedef float    f32x4 __attribute__((ext_vector_type(4)));

__device__ __forceinline__ void bar_lgkm() {
  asm volatile("s_waitcnt lgkmcnt(0)\n\ts_barrier" ::: "memory");
}

// lane L <-> lane L^16 exchange (BitMode xor=16, and=0x1F)
__device__ __forceinline__ float swz16(float v) {
  int i = __builtin_bit_cast(int, v);
  i = __builtin_amdgcn_ds_swizzle(i, 0x401F);
  return __builtin_bit_cast(float, i);
}

// raw 2^x (v_exp_f32); fallback keeps correctness if builtin absent
__device__ __forceinline__ float ex2(float x) {
#if __has_builtin(__builtin_amdgcn_exp2f)
  return __builtin_amdgcn_exp2f(x);
#else
  return __expf(x * 0.693147180559945309f);
#endif
}

// ---------------------------------------------------------------------------
// Weight pack: identical indexing to R5-R17, with per-gate log2e scaling.
// ---------------------------------------------------------------------------
__global__ void prep_weights(const float* __restrict__ eWih0,
                             const float* __restrict__ eWih,
                             const float* __restrict__ eWhh,
                             const float* __restrict__ dWih0,
                             const float* __restrict__ dWih,
                             const float* __restrict__ dWhh,
                             const float* __restrict__ linW,
                             _Float16* __restrict__ wq) {
  int idx = blockIdx.x * blockDim.x + threadIdx.x;
  if (idx >= NTOT) return;

  if (idx >= NPACK) {                      // ---- encoder pipeline pack ----
    int p    = idx - NPACK;
    int j    = p & 7;
    int lane = (p >> 3) & 63;
    int fe   = p >> 9;
    int kt   = fe & 3, nt = (fe >> 2) & 15, l = fe >> 6;
    int g    = nt * 16 + (lane & 15);
    int koff = ((lane >> 4) << 3) + j;
    float v = 0.0f;
    if (l == 0) {
      if (kt == 0)      v = (koff < NIN) ? eWih0[g * NIN + koff] : 0.0f;
      else if (kt == 1) v = 0.0f;
      else { int kk = (kt - 2) * 32 + koff; v = eWhh[g * H + PERM(kk)]; }
    } else {
      if (kt < 2) { int kk = kt * 32 + koff;
                    v = eWih[((l - 1) * 256 + g) * H + PERM(kk)]; }
      else        { int kk = (kt - 2) * 32 + koff;
                    v = eWhh[(l * 256 + g) * H + PERM(kk)]; }
    }
    v *= ((nt >> 2) == 2) ? SGG : SNEG;    // gate q = nt>>2
    wq[idx] = (_Float16)v;
    return;
  }

  if (idx >= PACK_H8 * 8) {                // ---- linW A-layout frags (unscaled) ----
    int p    = idx - PACK_H8 * 8;
    int j    = p & 7;
    int lane = (p >> 3) & 63;
    int fr   = p >> 9;
    int m    = lane & 15;
    int k    = fr * 32 + ((lane >> 4) << 3) + j;
    wq[idx] = (_Float16)((m < NIN) ? linW[m * H + k] : 0.0f);
    return;
  }

  // ---- col-sliced pack (decoder uses dec half) ----
  const int j    = idx & 7;
  const int lane = (idx >> 3) & 63;
  const int wv   = (idx >> 9) & 3;
  const int fh   = idx >> 11;
  const int f    = fh % FRAGS_HALF;
  const int half = fh / FRAGS_HALF;
  const float* Wi0 = half ? dWih0 : eWih0;
  const float* Wi  = half ? dWih  : eWih;
  const float* Wh  = half ? dWhh  : eWhh;
  int l, q, kt;
  if (f < 12) { l = 0; q = f / 3; kt = f % 3; }
  else        { int ff = f - 12; l = 1 + ff / 16; ff %= 16; q = ff / 4; kt = ff % 4; }
  const int g    = q * 64 + wv * 16 + (lane & 15);
  const int k_in = ((lane >> 4) << 3) + j;
  float v;
  if (l == 0) {
    if (kt == 0) v = (k_in < NIN) ? Wi0[g * NIN + k_in] : 0.0f;
    else         v = Wh[g * H + (kt - 1) * 32 + k_in];
  } else {
    if (kt < 2) v = Wi[((l - 1) * 256 + g) * H + kt * 32 + k_in];
    else        v = Wh[(l * 256 + g) * H + (kt - 2) * 32 + k_in];
  }
  v *= (q == 2) ? SGG : SNEG;
  wq[idx] = (_Float16)v;
}

// ---------------------------------------------------------------------------
__device__ __forceinline__ float rcpf(float x) { return __builtin_amdgcn_rcpf(x); }
__device__ __forceinline__ f32x4 mf(h8 a, h8 b, f32x4 c) {
  return __builtin_amdgcn_mfma_f32_16x16x32_f16(a, b, c, 0, 0, 0);
}
#define SPLAT(v) ((f32x4){(v), (v), (v), (v)})

// scaled-gate LSTM cell: inputs gi'=-l2e*gi, gf'=-l2e*gf, gg'=2l2e*gg,
// go'=-l2e*go. 5 exp2 + 3 rcp; 4 fewer dependent muls than __expf form.
__device__ __forceinline__ float ew_one(float gi, float gf, float gg, float go,
                                        float& c) {
  gg = fminf(fmaxf(gg, -GGCLAMP), GGCLAMP);
  float eni = ex2(gi);
  float e2g = ex2(gg);
  float enf = ex2(gf);
  float eno = ex2(go);
  c = c * rcpf(1.0f + enf) + (e2g - 1.0f) * rcpf((1.0f + eni) * (e2g + 1.0f));
  float cc = fminf(fmaxf(c, -20.0f), 20.0f);
  float e2c = ex2(cc * C2L2E);
  return (e2c - 1.0f) * rcpf((1.0f + eno) * (e2c + 1.0f));
}

__device__ __forceinline__ void cell_ew(f32x4 g0, f32x4 g1, f32x4 g2, f32x4 g3,
                                        f32x4& c, _Float16* outbuf,
                                        int quad, int r16, int sl) {
  #pragma unroll
  for (int r = 0; r < 4; r++) {
    float cv = c[r];
    float hv = ew_one(g0[r], g1[r], g2[r], g3[r], cv);
    c[r] = cv;
    outbuf[(quad * 4 + r) * HPAD + sl * 16 + r16] = (_Float16)hv;
  }
}

// compact role-split helpers (FMA order identical to R10 lineage)
__device__ __forceinline__ void precc(const h8 (&w)[8], h8 ar0, h8 ar1,
                                      f32x4 b, f32x4 (&ac)[4]) {
  #pragma unroll
  for (int q = 0; q < 4; q++)
    ac[q] = mf(ar1, w[q * 2 + 1], mf(ar0, w[q * 2], SPLAT(b[q])));
}
__device__ __forceinline__ void fireHc(const h8 (&w)[8], h8 ai0, h8 ai1,
                                       const f32x4 (&ac)[4], f32x4& c,
                                       _Float16* outbuf, int quad, int r16, int sl) {
  f32x4 g0 = mf(ai1, w[1], mf(ai0, w[0], ac[0]));
  f32x4 g1 = mf(ai1, w[3], mf(ai0, w[2], ac[1]));
  f32x4 g2 = mf(ai1, w[5], mf(ai0, w[4], ac[2]));
  f32x4 g3 = mf(ai1, w[7], mf(ai0, w[6], ac[3]));
  cell_ew(g0, g1, g2, g3, c, outbuf, quad, r16, sl);
}
__device__ __forceinline__ void fire0c(const h8 (&w)[4], h8 ax,
                                       const f32x4 (&ac)[4], f32x4& c,
                                       _Float16* outbuf, int quad, int r16, int sl) {
  f32x4 g0 = mf(ax, w[0], ac[0]);
  f32x4 g1 = mf(ax, w[1], ac[1]);
  f32x4 g2 = mf(ax, w[2], ac[2]);
  f32x4 g3 = mf(ax, w[3], ac[3]);
  cell_ew(g0, g1, g2, g3, c, outbuf, quad, r16, sl);
}
__device__ __forceinline__ void readA(const _Float16* buf, int r16, int quad,
                                      h8& a0, h8& a1) {
  a0 = *(const h8*)(buf + r16 * HPAD + quad * 8);
  a1 = *(const h8*)(buf + r16 * HPAD + 32 + quad * 8);
}

// ===========================================================================
// ENCODER kernel: 128 blocks x 512 threads, BB=16.  (R17 structure.)
// ===========================================================================
__global__ void __launch_bounds__(512, 2)
lstm_enc(const float* __restrict__ X,
         const float* __restrict__ encb,
         const h8* __restrict__ WQ,
         _Float16* __restrict__ hG,
         float* __restrict__ cG) {
  __shared__ _Float16 Hb[NL][2][16][HPAD];   // 18432 B
  __shared__ _Float16 Xb[2][16][HPAD];       //  4608 B

  const int tid  = threadIdx.x;
  const int wv   = tid >> 6;        // 0..7
  const int lane = tid & 63;
  const int quad = lane >> 4;
  const int r16  = lane & 15;
  const int grp  = wv & 1;          // col-half          (R17 map)
  const int lw   = (wv >> 1) & 3;   // layer             (R17 map)
  const int bbase = blockIdx.x * 16;

  {
    float* p = (float*)&Hb[0][0][0][0];
    for (int i = tid; i < 4608; i += 512) p[i] = 0.0f;
    float* px = (float*)&Xb[0][0][0];
    for (int i = tid; i < 1152; i += 512) px[i] = 0.0f;
  }
  if (tid < 16 * NIN) {
    int m = tid / NIN, ii = tid - m * NIN;
    Xb[0][m][ii] = (_Float16)X[((size_t)0 * BATCH + bbase + m) * NIN + ii];
  }

  // weights: 8 n-tiles {q*4 + 2*grp + cc}, 4 k-tiles each
  h8 we[8][4];
  #pragma unroll
  for (int q = 0; q < 4; q++)
    #pragma unroll
    for (int cc = 0; cc < 2; cc++)
      #pragma unroll
      for (int kt = 0; kt < 4; kt++)
        we[q * 2 + cc][kt] =
            WQ[(PACK_H8 + PROJ_H8) +
               ((lw * 64 + (q * 4 + 2 * grp + cc) * 4 + kt) * 64 + lane)];
  float ben[8];
  #pragma unroll
  for (int q = 0; q < 4; q++)
    #pragma unroll
    for (int cc = 0; cc < 2; cc++)
      ben[q * 2 + cc] = encb[lw * 256 + q * 64 + (2 * grp + cc) * 16 + r16] *
                        ((q == 2) ? SGG : SNEG);

  f32x4 ce[2];
  ce[0] = SPLAT(0.f); ce[1] = SPLAT(0.f);

  // 2-deep x prefetch: wave (lw=0, grp=0) = wv 0, lanes 0..47, 2 floats each
  const bool pfLane = (wv == 0) && (lane < 48);
  const int  pe0 = lane * 2, pe1 = pe0 + 1;
  const int  pm0 = pe0 / NIN, pc0 = pe0 % NIN;
  const int  pm1 = pe1 / NIN, pc1 = pe1 % NIN;
  float pf0 = 0.f, pf1 = 0.f;
  if (pfLane) {
    const float* xs = X + ((size_t)1 * BATCH + bbase) * NIN;
    pf0 = xs[pe0]; pf1 = xs[pe1];
  }

  __syncthreads();

  #pragma unroll 1
  for (int i = 0; i < S_LEN + NL - 1; i++) {     // 123 intervals
    const int p = i & 1;
    const bool active = (i >= lw) && (i - lw < S_LEN);
    if (active) {
      const _Float16* inb = (lw == 0) ? &Xb[p][0][0] : &Hb[lw - 1][p ^ 1][0][0];
      const _Float16* rcb = &Hb[lw][p ^ 1][0][0];
      h8 ai0 = *(const h8*)(inb + r16 * HPAD + quad * 8);
      h8 ai1 = {};
      if (lw) ai1 = *(const h8*)(inb + r16 * HPAD + 32 + quad * 8);
      h8 ar0 = *(const h8*)(rcb + r16 * HPAD + quad * 8);
      h8 ar1 = *(const h8*)(rcb + r16 * HPAD + 32 + quad * 8);

      float nf0 = 0.f, nf1 = 0.f;
      if (pfLane && (i + 2 < S_LEN)) {
        const float* xs = X + ((size_t)(i + 2) * BATCH + bbase) * NIN;
        nf0 = xs[pe0]; nf1 = xs[pe1];
      }

      f32x4 a[8];
      #pragma unroll
      for (int j = 0; j < 8; j++) {
        f32x4 t = SPLAT(ben[j]);
        t = mf(ai0, we[j][0], t);
        if (lw) t = mf(ai1, we[j][1], t);
        t = mf(ar0, we[j][2], t);
        t = mf(ar1, we[j][3], t);
        a[j] = t;
      }

      _Float16* wb = &Hb[lw][p][0][0];
      #pragma unroll
      for (int r = 0; r < 4; r++) {
        hh2 hv;
        #pragma unroll
        for (int cc = 0; cc < 2; cc++) {
          float cv = ce[cc][r];
          hv[cc] = (_Float16)ew_one(a[cc][r], a[2 + cc][r],
                                    a[4 + cc][r], a[6 + cc][r], cv);
          ce[cc][r] = cv;
        }
        // permuted layout: col c = ct*16+r16 lands at 4*r16+ct; ct = 2*grp+cc
        *(hh2*)(wb + (quad * 4 + r) * HPAD + 4 * r16 + 2 * grp) = hv;
      }

      if (pfLane && (i + 1 < S_LEN)) {
        Xb[p ^ 1][pm0][pc0] = (_Float16)pf0;
        Xb[p ^ 1][pm1][pc1] = (_Float16)pf1;
      }
      pf0 = nf0; pf1 = nf1;
    }
    bar_lgkm();
  }

  // ---- store c to global (per-lane direct) ----
  #pragma unroll
  for (int cc = 0; cc < 2; cc++)
    #pragma unroll
    for (int r = 0; r < 4; r++)
      cG[((size_t)lw * BATCH + bbase + quad * 4 + r) * H +
         (2 * grp + cc) * 16 + r16] = ce[cc][r];

  // ---- store final h (unpermute via PI) to global ----
  #pragma unroll
  for (int u = 0; u < 8; u++) {
    int i2 = tid + u * 512;
    int c = i2 & 63, m = (i2 >> 6) & 15, l = (i2 >> 10) & 3;
    hG[((size_t)l * BATCH + bbase + m) * H + c] =
        Hb[l][(l + 1) & 1][m][PI(c)];
  }
}

// ===========================================================================
// DECODER kernel: R14 structure verbatim (best). 128 blocks x 512 threads,
// 8 waves = 4 col-slices x {F,P}, 2 waves/SIMD, lane-contiguous AC handoff,
// F at setprio(1), swz16 xa build. Biases scaled per gate at load.
// ===========================================================================
__global__ void __launch_bounds__(512, 2)
lstm_dec(const float* __restrict__ X,
         const float* __restrict__ decb,
         const float* __restrict__ linb,
         const h8* __restrict__ WQ,
         const _Float16* __restrict__ hG,
         const float* __restrict__ cG,
         float* __restrict__ out) {
  __shared__ _Float16 Hb[NL][2][16][HPAD];   // 18432 B
  __shared__ f32x4 ACs[NL][4][4][64];        // 65536 B, [l][sl][j][lane]

  const int tid   = threadIdx.x;
  const int wv    = tid >> 6;        // 0..7
  const int sl    = wv & 3;          // col-slice
  const int roleP = wv >> 2;         // 0 = fire wave, 1 = prec wave
  const int lane  = tid & 63;
  const int quad  = lane >> 4;
  const int r16   = lane & 15;
  const int bbase = blockIdx.x * 16;

  // load encoder-final h into Hb[l][1] (all 512 threads)
  #pragma unroll
  for (int u = 0; u < 8; u++) {
    int i2 = tid + u * 512;
    int l = i2 >> 10, m = (i2 >> 6) & 15, c = i2 & 63;
    Hb[l][1][m][c] = hG[((size_t)l * BATCH + bbase + m) * H + c];
  }
  __syncthreads();   // h-load visible

  if (roleP) {
    // ================= P wave: recurrent precompute =================
    h8 wp0[8], wpH[3][8];
    #pragma unroll
    for (int e = 0; e < 8; e++) {
      int q = e >> 1, k = e & 1;
      wp0[e] = WQ[((FRAGS_HALF + q * 3 + 1 + k) * 4 + sl) * 64 + lane];
    }
    #pragma unroll
    for (int l = 0; l < 3; l++)
      #pragma unroll
      for (int e = 0; e < 8; e++) {
        int q = e >> 1, k = e & 1;
        wpH[l][e] = WQ[((FRAGS_HALF + 12 + l * 16 + q * 4 + 2 + k) * 4 + sl) * 64 + lane];
      }
    f32x4 b0, b1, b2, b3;
    #pragma unroll
    for (int q = 0; q < 4; q++) {
      const float s = (q == 2) ? SGG : SNEG;
      b0[q] = decb[0 * 256 + q * 64 + sl * 16 + r16] * s;
      b1[q] = decb[1 * 256 + q * 64 + sl * 16 + r16] * s;
      b2[q] = decb[2 * 256 + q * 64 + sl * 16 + r16] * s;
      b3[q] = decb[3 * 256 + q * 64 + sl * 16 + r16] * s;
    }

    // seed: prec layers 0,1,2 from encoder-final h
    {
      h8 s0, s1;
      f32x4 a[4];
      readA(&Hb[0][1][0][0], r16, quad, s0, s1);
      precc(wp0, s0, s1, b0, a);
      #pragma unroll
      for (int j = 0; j < 4; j++) ACs[0][sl][j][lane] = a[j];
      readA(&Hb[1][1][0][0], r16, quad, s0, s1);
      precc(wpH[0], s0, s1, b1, a);
      #pragma unroll
      for (int j = 0; j < 4; j++) ACs[1][sl][j][lane] = a[j];
      readA(&Hb[2][1][0][0], r16, quad, s0, s1);
      precc(wpH[1], s0, s1, b2, a);
      #pragma unroll
      for (int j = 0; j < 4; j++) ACs[2][sl][j][lane] = a[j];
    }
    bar_lgkm();   // matches F's pre-loop bar

    #pragma unroll 1
    for (int t = 0; t < TLEN; t++) {
      const int cur = t & 1, prv = cur ^ 1;
      { // ---- A: prec layer3 from h3[prv] ----
        h8 a0, a1; readA(&Hb[3][prv][0][0], r16, quad, a0, a1);
        f32x4 a[4]; precc(wpH[2], a0, a1, b3, a);
        #pragma unroll
        for (int j = 0; j < 4; j++) ACs[3][sl][j][lane] = a[j];
        bar_lgkm();
      }
      { // ---- B: prec layer0 from h0[cur] ----
        h8 a0, a1; readA(&Hb[0][cur][0][0], r16, quad, a0, a1);
        f32x4 a[4]; precc(wp0, a0, a1, b0, a);
        #pragma unroll
        for (int j = 0; j < 4; j++) ACs[0][sl][j][lane] = a[j];
        bar_lgkm();
      }
      { // ---- C: prec layer1 from h1[cur] ----
        h8 a0, a1; readA(&Hb[1][cur][0][0], r16, quad, a0, a1);
        f32x4 a[4]; precc(wpH[0], a0, a1, b1, a);
        #pragma unroll
        for (int j = 0; j < 4; j++) ACs[1][sl][j][lane] = a[j];
        bar_lgkm();
      }
      { // ---- D: prec layer2 from h2[cur] ----
        h8 a0, a1; readA(&Hb[2][cur][0][0], r16, quad, a0, a1);
        f32x4 a[4]; precc(wpH[1], a0, a1, b2, a);
        #pragma unroll
        for (int j = 0; j < 4; j++) ACs[2][sl][j][lane] = a[j];
        bar_lgkm();
      }
    }
  } else {
    // ================= F wave: fire + ew + proj (setprio 1) =================
    h8 wf0[4], wfH[3][8];
    #pragma unroll
    for (int q = 0; q < 4; q++)
      wf0[q] = WQ[((FRAGS_HALF + q * 3) * 4 + sl) * 64 + lane];
    #pragma unroll
    for (int l = 0; l < 3; l++)
      #pragma unroll
      for (int e = 0; e < 8; e++) {
        int q = e >> 1, k = e & 1;
        wfH[l][e] = WQ[((FRAGS_HALF + 12 + l * 16 + q * 4 + k) * 4 + sl) * 64 + lane];
      }

    // c slices
    f32x4 cs0, cs1, cs2, cs3;
    #pragma unroll
    for (int r = 0; r < 4; r++) {
      cs0[r] = cG[((size_t)0 * BATCH + bbase + quad * 4 + r) * H + sl * 16 + r16];
      cs1[r] = cG[((size_t)1 * BATCH + bbase + quad * 4 + r) * H + sl * 16 + r16];
      cs2[r] = cG[((size_t)2 * BATCH + bbase + quad * 4 + r) * H + sl * 16 + r16];
      cs3[r] = cG[((size_t)3 * BATCH + bbase + quad * 4 + r) * H + sl * 16 + r16];
    }

    h8 lwA0 = WQ[PACK_H8 + lane];
    h8 lwA1 = WQ[PACK_H8 + 64 + lane];
    f32x4 lbq;
    #pragma unroll
    for (int r = 0; r < 4; r++)
      lbq[r] = (quad * 4 + r < NIN) ? linb[quad * 4 + r] : 0.0f;

    // x[119] A-frag (k = quad*8+j; only k<6 real)
    h8 xseed = {};
    if (quad == 0) {
      const float* xs = X + ((size_t)(S_LEN - 1) * BATCH + bbase + r16) * NIN;
      #pragma unroll
      for (int j = 0; j < 6; j++) xseed[j] = (_Float16)xs[j];
    }

    bar_lgkm();   // matches P's seed bar

    __builtin_amdgcn_s_setprio(1);   // F gates every barrier; bias issue to it

    #pragma unroll 1
    for (int t = 0; t < TLEN; t++) {
      const int cur = t & 1, prv = cur ^ 1;
      { // ---- A: proj(h3[t-1]) + layer-0 fire ----
        h8 ar0, ar1;
        readA(&Hb[3][prv][0][0], r16, quad, ar0, ar1);
        h8 ax;
        if (t == 0) {
          ax = xseed;
        } else {
          f32x4 ap = lbq;
          ap = mf(lwA0, ar0, ap);     // A = linW (m=feature), B = h3 (n=batch)
          ap = mf(lwA1, ar1, ap);
          if (sl == 0) {
            #pragma unroll
            for (int r = 0; r < 4; r++) {
              const int fm = quad * 4 + r;
              if (fm < NIN)
                out[((size_t)(t - 1) * BATCH + bbase + r16) * NIN + fm] = ap[r];
            }
          }
          // xa consumers are quad==0 lanes: shfl(ap[r], r16) is identity there;
          // feats 4,5 come from quad1 = lane^16 -> ds_swizzle xor-16.
          float x4 = swz16(ap[0]);
          float x5 = swz16(ap[1]);
          h8 xa = {};
          xa[0] = (_Float16)ap[0]; xa[1] = (_Float16)ap[1];
          xa[2] = (_Float16)ap[2]; xa[3] = (_Float16)ap[3];
          xa[4] = (_Float16)x4;    xa[5] = (_Float16)x5;
          h8 zz = {};
          ax = (quad == 0) ? xa : zz;
        }
        f32x4 ac[4];
        #pragma unroll
        for (int j = 0; j < 4; j++) ac[j] = ACs[0][sl][j][lane];
        fire0c(wf0, ax, ac, cs0, &Hb[0][cur][0][0], quad, r16, sl);
        bar_lgkm();
      }
      { // ---- B: fire layer1 ----
        h8 ai0, ai1;
        readA(&Hb[0][cur][0][0], r16, quad, ai0, ai1);
        f32x4 ac[4];
        #pragma unroll
        for (int j = 0; j < 4; j++) ac[j] = ACs[1][sl][j][lane];
        fireHc(wfH[0], ai0, ai1, ac, cs1, &Hb[1][cur][0][0], quad, r16, sl);
        bar_lgkm();
      }
      { // ---- C: fire layer2 ----
        h8 ai0, ai1;
        readA(&Hb[1][cur][0][0], r16, quad, ai0, ai1);
        f32x4 ac[4];
        #pragma unroll
        for (int j = 0; j < 4; j++) ac[j] = ACs[2][sl][j][lane];
        fireHc(wfH[1], ai0, ai1, ac, cs2, &Hb[2][cur][0][0], quad, r16, sl);
        bar_lgkm();
      }
      { // ---- D: fire layer3 ----
        h8 ai0, ai1;
        readA(&Hb[2][cur][0][0], r16, quad, ai0, ai1);
        f32x4 ac[4];
        #pragma unroll
        for (int j = 0; j < 4; j++) ac[j] = ACs[3][sl][j][lane];
        fireHc(wfH[2], ai0, ai1, ac, cs3, &Hb[3][cur][0][0], quad, r16, sl);
        bar_lgkm();
      }
    }

    __builtin_amdgcn_s_setprio(0);

    // epilogue: out[TLEN-1] from h3 of last step (parity 1)
    if (sl == 0) {
      h8 ar0, ar1;
      readA(&Hb[3][1][0][0], r16, quad, ar0, ar1);
      f32x4 ap = lbq;
      ap = mf(lwA0, ar0, ap);
      ap = mf(lwA1, ar1, ap);
      #pragma unroll
      for (int r = 0; r < 4; r++) {
        const int fm = quad * 4 + r;
        if (fm < NIN)
          out[((size_t)(TLEN - 1) * BATCH + bbase + r16) * NIN + fm] = ap[r];
      }
    }
  }
}

// ---------------------------------------------------------------------------
extern "C" void kernel_launch(void* const* d_in, const int* in_sizes, int n_in,
                              void* d_out, int out_size, void* d_ws, size_t ws_size,
                              hipStream_t stream) {
  const float* X     = (const float*)d_in[0];
  const float* eWih0 = (const float*)d_in[1];
  const float* eWih  = (const float*)d_in[2];
  const float* eWhh  = (const float*)d_in[3];
  const float* eb    = (const float*)d_in[4];
  const float* dWih0 = (const float*)d_in[5];
  const float* dWih  = (const float*)d_in[6];
  const float* dWhh  = (const float*)d_in[7];
  const float* db    = (const float*)d_in[8];
  const float* lW    = (const float*)d_in[9];
  const float* lb    = (const float*)d_in[10];

  _Float16* wq = (_Float16*)d_ws;
  _Float16* hG = (_Float16*)((char*)d_ws + WS_HOFF);
  float*    cG = (float*)((char*)d_ws + WS_COFF);

  prep_weights<<<(NTOT + 255) / 256, 256, 0, stream>>>(
      eWih0, eWih, eWhh, dWih0, dWih, dWhh, lW, wq);

  lstm_enc<<<BATCH / 16, 512, 0, stream>>>(
      X, eb, (const h8*)wq, hG, cG);

  lstm_dec<<<BATCH / 16, 512, 0, stream>>>(
      X, db, lb, (const h8*)wq, hG, cG, (float*)d_out);
}